// Round 1
// baseline (342.643 us; speedup 1.0000x reference)
//
#include <hip/hip_runtime.h>
#include <stdint.h>

// B=16, N=1024, D=768 fixed for this problem.
#define BB 16
#define NN 1024
#define DD 768

typedef unsigned short u16;
using bf16x8 = __attribute__((ext_vector_type(8))) __bf16;
using f32x4  = __attribute__((ext_vector_type(4))) float;

__device__ inline u16 f2bf(float x) {
    uint32_t u = __float_as_uint(x);
    u += 0x7fffu + ((u >> 16) & 1u);   // round-to-nearest-even
    return (u16)(u >> 16);
}

__device__ inline void gl_lds16(const void* g, void* l) {
    __builtin_amdgcn_global_load_lds(
        (__attribute__((address_space(1))) void*)g,
        (__attribute__((address_space(3))) void*)l,
        16, 0, 0);
}

// ---------------------------------------------------------------------------
// K1: fp32 [B][N][D] -> bf16 [B][N][D] and bf16 transposed [B][D][N]
// grid (D/32, N/32, B), block 256
// ---------------------------------------------------------------------------
__global__ __launch_bounds__(256) void cast_transpose(
    const float* __restrict__ in, u16* __restrict__ outb, u16* __restrict__ outT)
{
    __shared__ u16 tile[32][33];
    const int b  = blockIdx.z;
    const int n0 = blockIdx.y * 32;
    const int d0 = blockIdx.x * 32;
    const int t  = threadIdx.x;
    const int c  = t & 31;
    const int r0 = t >> 5;   // 0..7

    const float* src = in + ((size_t)b * NN + n0) * DD + d0;
#pragma unroll
    for (int i = 0; i < 4; ++i) {
        int r = r0 + 8 * i;
        float x = src[(size_t)r * DD + c];
        u16 h = f2bf(x);
        outb[((size_t)b * NN + n0 + r) * DD + d0 + c] = h;
        tile[r][c] = h;
    }
    __syncthreads();
#pragma unroll
    for (int i = 0; i < 4; ++i) {
        int r = r0 + 8 * i;   // d offset within tile
        outT[((size_t)b * DD + d0 + r) * NN + n0 + c] = tile[c][r];
    }
}

// ---------------------------------------------------------------------------
// K2: C[b][i][j] = sum_k A[b][i][k] * B[b][j][k]   (both row-major, K contig)
// A: [M x K] bf16, B: [Ncols x K] bf16, C: [M x ldc] fp32
// tile 128x128, BK=64, 4 waves, 16x16x32 MFMA, XOR-swizzled LDS
// grid (Ncols/128, M/128, batch), block 256
// ---------------------------------------------------------------------------
__global__ __launch_bounds__(256) void gemm_bt(
    const u16* __restrict__ A, const u16* __restrict__ B, float* __restrict__ C,
    const int K, const int ldc, const size_t sA, const size_t sB, const size_t sC)
{
    __shared__ u16 lsA[128 * 64];
    __shared__ u16 lsB[128 * 64];

    const int tid = threadIdx.x;
    const int w  = tid >> 6;
    const int l  = tid & 63;
    const int wm = w >> 1, wn = w & 1;

    const u16* Ab = A + (size_t)blockIdx.z * sA + (size_t)blockIdx.y * 128 * K;
    const u16* Bb = B + (size_t)blockIdx.z * sB + (size_t)blockIdx.x * 128 * K;

    // staging: each wave issues 4 A-loads + 4 B-loads of 1KB (global_load_lds x16B)
    const int lrow  = l >> 3;         // 0..7 (row within 8-row chunk)
    const int lslot = l & 7;          // 16B slot within 128B row
    const int gslot = lslot ^ lrow;   // pre-swizzled global source slot

    const u16* pA[4]; const u16* pB[4];
    char* dA[4]; char* dB[4];
#pragma unroll
    for (int i = 0; i < 4; ++i) {
        int row = w * 32 + i * 8 + lrow;          // 0..127
        pA[i] = Ab + (size_t)row * K + gslot * 8;
        pB[i] = Bb + (size_t)row * K + gslot * 8;
        dA[i] = (char*)lsA + (w * 4 + i) * 1024;
        dB[i] = (char*)lsB + (w * 4 + i) * 1024;
    }

    // read-side fragment addressing
    const int lg = l >> 4;   // 0..3
    const int lr = l & 15;
    int rbA[4], rxA[4], rbB[4], rxB[4];
#pragma unroll
    for (int m = 0; m < 4; ++m) {
        int rA = wm * 64 + m * 16 + lr;
        rbA[m] = rA * 128; rxA[m] = rA & 7;
        int rB = wn * 64 + m * 16 + lr;
        rbB[m] = rB * 128; rxB[m] = rB & 7;
    }

    f32x4 acc[4][4];
#pragma unroll
    for (int i = 0; i < 4; ++i)
#pragma unroll
        for (int j = 0; j < 4; ++j) acc[i][j] = (f32x4){0.f, 0.f, 0.f, 0.f};

    const char* lA = (const char*)lsA;
    const char* lB = (const char*)lsB;

    const int ksteps = K >> 6;
    for (int kt = 0; kt < ksteps; ++kt) {
#pragma unroll
        for (int i = 0; i < 4; ++i) {
            gl_lds16(pA[i], dA[i]);
            gl_lds16(pB[i], dB[i]);
        }
        asm volatile("s_waitcnt vmcnt(0)" ::: "memory");
        __syncthreads();

#pragma unroll
        for (int kk = 0; kk < 2; ++kk) {
            bf16x8 a[4], b[4];
#pragma unroll
            for (int m = 0; m < 4; ++m) {
                int slot = kk * 4 + lg;
                a[m] = *(const bf16x8*)(lA + rbA[m] + ((slot ^ rxA[m]) << 4));
                b[m] = *(const bf16x8*)(lB + rbB[m] + ((slot ^ rxB[m]) << 4));
            }
#pragma unroll
            for (int m = 0; m < 4; ++m)
#pragma unroll
                for (int n = 0; n < 4; ++n)
                    acc[m][n] = __builtin_amdgcn_mfma_f32_16x16x32_bf16(
                        a[m], b[n], acc[m][n], 0, 0, 0);
        }
        __syncthreads();
#pragma unroll
        for (int i = 0; i < 4; ++i) { pA[i] += 64; pB[i] += 64; }
    }

    float* Cb = C + (size_t)blockIdx.z * sC;
    const int crow = blockIdx.y * 128 + wm * 64 + lg * 4;
    const int ccol = blockIdx.x * 128 + wn * 64 + lr;
#pragma unroll
    for (int m = 0; m < 4; ++m)
#pragma unroll
        for (int n = 0; n < 4; ++n)
#pragma unroll
            for (int r = 0; r < 4; ++r)
                Cb[(size_t)(crow + m * 16 + r) * ldc + ccol + n * 16] = acc[m][n][r];
}

// ---------------------------------------------------------------------------
// K3: row softmax over 1024 fp32 -> bf16. grid = rows, block 256
// ---------------------------------------------------------------------------
__global__ __launch_bounds__(256) void softmax_rows(
    const float* __restrict__ sim, u16* __restrict__ attn)
{
    __shared__ float red[4];
    const size_t row = blockIdx.x;
    const float* p = sim + row * NN;
    const int t = threadIdx.x;

    float v0 = p[t], v1 = p[t + 256], v2 = p[t + 512], v3 = p[t + 768];
    float m = fmaxf(fmaxf(v0, v1), fmaxf(v2, v3));
#pragma unroll
    for (int o = 32; o > 0; o >>= 1) m = fmaxf(m, __shfl_xor(m, o, 64));
    if ((t & 63) == 0) red[t >> 6] = m;
    __syncthreads();
    m = fmaxf(fmaxf(red[0], red[1]), fmaxf(red[2], red[3]));
    __syncthreads();

    float e0 = __expf(v0 - m), e1 = __expf(v1 - m);
    float e2 = __expf(v2 - m), e3 = __expf(v3 - m);
    float s = e0 + e1 + e2 + e3;
#pragma unroll
    for (int o = 32; o > 0; o >>= 1) s += __shfl_xor(s, o, 64);
    if ((t & 63) == 0) red[t >> 6] = s;
    __syncthreads();
    s = red[0] + red[1] + red[2] + red[3];
    const float inv = 1.0f / s;

    u16* q = attn + row * NN;
    q[t]       = f2bf(e0 * inv);
    q[t + 256] = f2bf(e1 * inv);
    q[t + 512] = f2bf(e2 * inv);
    q[t + 768] = f2bf(e3 * inv);
}

// ---------------------------------------------------------------------------
// K4: in-place io = io/max(||io||,eps) + 2*img, per row of 768. grid = B*N
// ---------------------------------------------------------------------------
__global__ __launch_bounds__(256) void norm_add(
    float* __restrict__ io, const float* __restrict__ img)
{
    __shared__ float red[4];
    const size_t row = blockIdx.x;
    float* p = io + row * DD;
    const float* q = img + row * DD;
    const int t = threadIdx.x;

    float x0 = p[t], x1 = p[t + 256], x2 = p[t + 512];
    float s = x0 * x0 + x1 * x1 + x2 * x2;
#pragma unroll
    for (int o = 32; o > 0; o >>= 1) s += __shfl_xor(s, o, 64);
    if ((t & 63) == 0) red[t >> 6] = s;
    __syncthreads();
    s = red[0] + red[1] + red[2] + red[3];
    const float sc = 1.0f / fmaxf(sqrtf(s), 1e-12f);

    p[t]       = x0 * sc + 2.0f * q[t];
    p[t + 256] = x1 * sc + 2.0f * q[t + 256];
    p[t + 512] = x2 * sc + 2.0f * q[t + 512];
}

// ---------------------------------------------------------------------------
extern "C" void kernel_launch(void* const* d_in, const int* in_sizes, int n_in,
                              void* d_out, int out_size, void* d_ws, size_t ws_size,
                              hipStream_t stream)
{
    const float* img1 = (const float*)d_in[0];
    const float* img2 = (const float*)d_in[1];
    float* out = (float*)d_out;

    const size_t NBD = (size_t)BB * NN * DD;       // 12582912 elems
    u16* i1b = (u16*)d_ws;
    u16* i2b = i1b + NBD;
    u16* i1t = i2b + NBD;
    u16* i2t = i1t + NBD;
    char* rest = (char*)(i2t + NBD);
    const size_t baseBytes = 4 * NBD * sizeof(u16);

    int CB = 16;
    while (CB > 1 && baseBytes + (size_t)CB * NN * NN * 6 > ws_size) CB >>= 1;

    float* sim = (float*)rest;
    u16* attn = (u16*)(rest + (size_t)CB * NN * NN * 4);

    const size_t sND = (size_t)NN * DD;   // 786432
    const size_t sNNe = (size_t)NN * NN;  // 1048576

    cast_transpose<<<dim3(DD / 32, NN / 32, BB), 256, 0, stream>>>(img1, i1b, i1t);
    cast_transpose<<<dim3(DD / 32, NN / 32, BB), 256, 0, stream>>>(img2, i2b, i2t);

    // Direction A: Q=img1, K/V=img2 -> output slot 1 (out2)
    for (int b0 = 0; b0 < BB; b0 += CB) {
        gemm_bt<<<dim3(NN / 128, NN / 128, CB), 256, 0, stream>>>(
            i1b + (size_t)b0 * sND, i2b + (size_t)b0 * sND, sim,
            DD, NN, sND, sND, sNNe);
        softmax_rows<<<dim3(CB * NN), 256, 0, stream>>>(sim, attn);
        gemm_bt<<<dim3(DD / 128, NN / 128, CB), 256, 0, stream>>>(
            attn, i2t + (size_t)b0 * sND, out + NBD + (size_t)b0 * sND,
            NN, DD, sNNe, sND, sND);
    }
    norm_add<<<dim3(BB * NN), 256, 0, stream>>>(out + NBD, img2);

    // Direction B: Q=img2, K/V=img1 -> output slot 0 (out1)
    for (int b0 = 0; b0 < BB; b0 += CB) {
        gemm_bt<<<dim3(NN / 128, NN / 128, CB), 256, 0, stream>>>(
            i2b + (size_t)b0 * sND, i1b + (size_t)b0 * sND, sim,
            DD, NN, sND, sND, sNNe);
        softmax_rows<<<dim3(CB * NN), 256, 0, stream>>>(sim, attn);
        gemm_bt<<<dim3(DD / 128, NN / 128, CB), 256, 0, stream>>>(
            attn, i1t + (size_t)b0 * sND, out + (size_t)b0 * sND,
            NN, DD, sNNe, sND, sND);
    }
    norm_add<<<dim3(BB * NN), 256, 0, stream>>>(out, img1);
}

// Round 2
// 330.129 us; speedup vs baseline: 1.0379x; 1.0379x over previous
//
#include <hip/hip_runtime.h>
#include <stdint.h>

// B=16, N=1024, D=768 fixed for this problem.
#define BB 16
#define NN 1024
#define DD 768

typedef unsigned short u16;
using bf16x8 = __attribute__((ext_vector_type(8))) __bf16;
using f32x4  = __attribute__((ext_vector_type(4))) float;

__device__ inline u16 f2bf(float x) {
    uint32_t u = __float_as_uint(x);
    u += 0x7fffu + ((u >> 16) & 1u);   // round-to-nearest-even
    return (u16)(u >> 16);
}

__device__ inline void gl_lds16(const void* g, void* l) {
    __builtin_amdgcn_global_load_lds(
        (__attribute__((address_space(1))) void*)g,
        (__attribute__((address_space(3))) void*)l,
        16, 0, 0);
}

// ---------------------------------------------------------------------------
// K1: fp32 [B][N][D] -> bf16 [B][N][D] and bf16 transposed [B][D][N]
// grid (D/32, N/32, B), block 256
// ---------------------------------------------------------------------------
__global__ __launch_bounds__(256) void cast_transpose(
    const float* __restrict__ in, u16* __restrict__ outb, u16* __restrict__ outT)
{
    __shared__ u16 tile[32][33];
    const int b  = blockIdx.z;
    const int n0 = blockIdx.y * 32;
    const int d0 = blockIdx.x * 32;
    const int t  = threadIdx.x;
    const int c  = t & 31;
    const int r0 = t >> 5;   // 0..7

    const float* src = in + ((size_t)b * NN + n0) * DD + d0;
#pragma unroll
    for (int i = 0; i < 4; ++i) {
        int r = r0 + 8 * i;
        float x = src[(size_t)r * DD + c];
        u16 h = f2bf(x);
        outb[((size_t)b * NN + n0 + r) * DD + d0 + c] = h;
        tile[r][c] = h;
    }
    __syncthreads();
#pragma unroll
    for (int i = 0; i < 4; ++i) {
        int r = r0 + 8 * i;   // d offset within tile
        outT[((size_t)b * DD + d0 + r) * NN + n0 + c] = tile[c][r];
    }
}

// ---------------------------------------------------------------------------
// K2: C[b][i][j] = sum_k A[b][i][k] * B[b][j][k]   (both row-major, K contig)
// A: [M x K] bf16, B: [Ncols x K] bf16, C: [M x ldc] fp32
// tile 128x128, BK=64, 4 waves, 16x16x32 MFMA, XOR-swizzled LDS.
// XCD-aware bijective block swizzle (T1): nwg is always %8==0 here
// (gx*gy*gz in {1024,768,512,384,256,192,128,96,64,48}), batch decoded
// SLOWEST so each XCD owns ~nwg/8 consecutive tiles = ~2 whole batches
// (A+B = 3.1 MB/batch fits the 4 MB per-XCD L2).
// grid (Ncols/128, M/128, batch), block 256
// ---------------------------------------------------------------------------
__global__ __launch_bounds__(256) void gemm_bt(
    const u16* __restrict__ A, const u16* __restrict__ B, float* __restrict__ C,
    const int K, const int ldc, const size_t sA, const size_t sB, const size_t sC)
{
    __shared__ u16 lsA[128 * 64];
    __shared__ u16 lsB[128 * 64];

    // --- XCD swizzle: dispatch-order id -> owned tile id ---
    const int gx = gridDim.x, gy = gridDim.y;
    const int nwg = gx * gy * gridDim.z;
    int bid = blockIdx.x + gx * (blockIdx.y + gy * blockIdx.z);
    bid = (bid & 7) * (nwg >> 3) + (bid >> 3);
    const int gxy = gx * gy;
    const int bz = bid / gxy;
    const int rem = bid - bz * gxy;
    const int by = rem / gx;
    const int bx = rem - by * gx;

    const int tid = threadIdx.x;
    const int w  = tid >> 6;
    const int l  = tid & 63;
    const int wm = w >> 1, wn = w & 1;

    const u16* Ab = A + (size_t)bz * sA + (size_t)by * 128 * K;
    const u16* Bb = B + (size_t)bz * sB + (size_t)bx * 128 * K;

    // staging: each wave issues 4 A-loads + 4 B-loads of 1KB (global_load_lds x16B)
    const int lrow  = l >> 3;         // 0..7 (row within 8-row chunk)
    const int lslot = l & 7;          // 16B slot within 128B row
    const int gslot = lslot ^ lrow;   // pre-swizzled global source slot

    const u16* pA[4]; const u16* pB[4];
    char* dA[4]; char* dB[4];
#pragma unroll
    for (int i = 0; i < 4; ++i) {
        int row = w * 32 + i * 8 + lrow;          // 0..127
        pA[i] = Ab + (size_t)row * K + gslot * 8;
        pB[i] = Bb + (size_t)row * K + gslot * 8;
        dA[i] = (char*)lsA + (w * 4 + i) * 1024;
        dB[i] = (char*)lsB + (w * 4 + i) * 1024;
    }

    // read-side fragment addressing
    const int lg = l >> 4;   // 0..3
    const int lr = l & 15;
    int rbA[4], rxA[4], rbB[4], rxB[4];
#pragma unroll
    for (int m = 0; m < 4; ++m) {
        int rA = wm * 64 + m * 16 + lr;
        rbA[m] = rA * 128; rxA[m] = rA & 7;
        int rB = wn * 64 + m * 16 + lr;
        rbB[m] = rB * 128; rxB[m] = rB & 7;
    }

    f32x4 acc[4][4];
#pragma unroll
    for (int i = 0; i < 4; ++i)
#pragma unroll
        for (int j = 0; j < 4; ++j) acc[i][j] = (f32x4){0.f, 0.f, 0.f, 0.f};

    const char* lA = (const char*)lsA;
    const char* lB = (const char*)lsB;

    const int ksteps = K >> 6;
    for (int kt = 0; kt < ksteps; ++kt) {
#pragma unroll
        for (int i = 0; i < 4; ++i) {
            gl_lds16(pA[i], dA[i]);
            gl_lds16(pB[i], dB[i]);
        }
        asm volatile("s_waitcnt vmcnt(0)" ::: "memory");
        __syncthreads();

#pragma unroll
        for (int kk = 0; kk < 2; ++kk) {
            bf16x8 a[4], b[4];
#pragma unroll
            for (int m = 0; m < 4; ++m) {
                int slot = kk * 4 + lg;
                a[m] = *(const bf16x8*)(lA + rbA[m] + ((slot ^ rxA[m]) << 4));
                b[m] = *(const bf16x8*)(lB + rbB[m] + ((slot ^ rxB[m]) << 4));
            }
#pragma unroll
            for (int m = 0; m < 4; ++m)
#pragma unroll
                for (int n = 0; n < 4; ++n)
                    acc[m][n] = __builtin_amdgcn_mfma_f32_16x16x32_bf16(
                        a[m], b[n], acc[m][n], 0, 0, 0);
        }
        __syncthreads();
#pragma unroll
        for (int i = 0; i < 4; ++i) { pA[i] += 64; pB[i] += 64; }
    }

    float* Cb = C + (size_t)bz * sC;
    const int crow = by * 128 + wm * 64 + lg * 4;
    const int ccol = bx * 128 + wn * 64 + lr;
#pragma unroll
    for (int m = 0; m < 4; ++m)
#pragma unroll
        for (int n = 0; n < 4; ++n)
#pragma unroll
            for (int r = 0; r < 4; ++r)
                Cb[(size_t)(crow + m * 16 + r) * ldc + ccol + n * 16] = acc[m][n][r];
}

// ---------------------------------------------------------------------------
// K3: row softmax over 1024 fp32 -> bf16. grid = rows, block 256
// ---------------------------------------------------------------------------
__global__ __launch_bounds__(256) void softmax_rows(
    const float* __restrict__ sim, u16* __restrict__ attn)
{
    __shared__ float red[4];
    const size_t row = blockIdx.x;
    const float* p = sim + row * NN;
    const int t = threadIdx.x;

    float v0 = p[t], v1 = p[t + 256], v2 = p[t + 512], v3 = p[t + 768];
    float m = fmaxf(fmaxf(v0, v1), fmaxf(v2, v3));
#pragma unroll
    for (int o = 32; o > 0; o >>= 1) m = fmaxf(m, __shfl_xor(m, o, 64));
    if ((t & 63) == 0) red[t >> 6] = m;
    __syncthreads();
    m = fmaxf(fmaxf(red[0], red[1]), fmaxf(red[2], red[3]));
    __syncthreads();

    float e0 = __expf(v0 - m), e1 = __expf(v1 - m);
    float e2 = __expf(v2 - m), e3 = __expf(v3 - m);
    float s = e0 + e1 + e2 + e3;
#pragma unroll
    for (int o = 32; o > 0; o >>= 1) s += __shfl_xor(s, o, 64);
    if ((t & 63) == 0) red[t >> 6] = s;
    __syncthreads();
    s = red[0] + red[1] + red[2] + red[3];
    const float inv = 1.0f / s;

    u16* q = attn + row * NN;
    q[t]       = f2bf(e0 * inv);
    q[t + 256] = f2bf(e1 * inv);
    q[t + 512] = f2bf(e2 * inv);
    q[t + 768] = f2bf(e3 * inv);
}

// ---------------------------------------------------------------------------
// K4: in-place io = io/max(||io||,eps) + 2*img, per row of 768. grid = B*N
// ---------------------------------------------------------------------------
__global__ __launch_bounds__(256) void norm_add(
    float* __restrict__ io, const float* __restrict__ img)
{
    __shared__ float red[4];
    const size_t row = blockIdx.x;
    float* p = io + row * DD;
    const float* q = img + row * DD;
    const int t = threadIdx.x;

    float x0 = p[t], x1 = p[t + 256], x2 = p[t + 512];
    float s = x0 * x0 + x1 * x1 + x2 * x2;
#pragma unroll
    for (int o = 32; o > 0; o >>= 1) s += __shfl_xor(s, o, 64);
    if ((t & 63) == 0) red[t >> 6] = s;
    __syncthreads();
    s = red[0] + red[1] + red[2] + red[3];
    const float sc = 1.0f / fmaxf(sqrtf(s), 1e-12f);

    p[t]       = x0 * sc + 2.0f * q[t];
    p[t + 256] = x1 * sc + 2.0f * q[t + 256];
    p[t + 512] = x2 * sc + 2.0f * q[t + 512];
}

// ---------------------------------------------------------------------------
extern "C" void kernel_launch(void* const* d_in, const int* in_sizes, int n_in,
                              void* d_out, int out_size, void* d_ws, size_t ws_size,
                              hipStream_t stream)
{
    const float* img1 = (const float*)d_in[0];
    const float* img2 = (const float*)d_in[1];
    float* out = (float*)d_out;

    const size_t NBD = (size_t)BB * NN * DD;       // 12582912 elems
    u16* i1b = (u16*)d_ws;
    u16* i2b = i1b + NBD;
    u16* i1t = i2b + NBD;
    u16* i2t = i1t + NBD;
    char* rest = (char*)(i2t + NBD);
    const size_t baseBytes = 4 * NBD * sizeof(u16);

    int CB = 16;
    while (CB > 1 && baseBytes + (size_t)CB * NN * NN * 6 > ws_size) CB >>= 1;

    float* sim = (float*)rest;
    u16* attn = (u16*)(rest + (size_t)CB * NN * NN * 4);

    const size_t sND = (size_t)NN * DD;   // 786432
    const size_t sNNe = (size_t)NN * NN;  // 1048576

    cast_transpose<<<dim3(DD / 32, NN / 32, BB), 256, 0, stream>>>(img1, i1b, i1t);
    cast_transpose<<<dim3(DD / 32, NN / 32, BB), 256, 0, stream>>>(img2, i2b, i2t);

    // Direction A: Q=img1, K/V=img2 -> output slot 1 (out2)
    for (int b0 = 0; b0 < BB; b0 += CB) {
        gemm_bt<<<dim3(NN / 128, NN / 128, CB), 256, 0, stream>>>(
            i1b + (size_t)b0 * sND, i2b + (size_t)b0 * sND, sim,
            DD, NN, sND, sND, sNNe);
        softmax_rows<<<dim3(CB * NN), 256, 0, stream>>>(sim, attn);
        gemm_bt<<<dim3(DD / 128, NN / 128, CB), 256, 0, stream>>>(
            attn, i2t + (size_t)b0 * sND, out + NBD + (size_t)b0 * sND,
            NN, DD, sNNe, sND, sND);
    }
    norm_add<<<dim3(BB * NN), 256, 0, stream>>>(out + NBD, img2);

    // Direction B: Q=img2, K/V=img1 -> output slot 0 (out1)
    for (int b0 = 0; b0 < BB; b0 += CB) {
        gemm_bt<<<dim3(NN / 128, NN / 128, CB), 256, 0, stream>>>(
            i2b + (size_t)b0 * sND, i1b + (size_t)b0 * sND, sim,
            DD, NN, sND, sND, sNNe);
        softmax_rows<<<dim3(CB * NN), 256, 0, stream>>>(sim, attn);
        gemm_bt<<<dim3(DD / 128, NN / 128, CB), 256, 0, stream>>>(
            attn, i1t + (size_t)b0 * sND, out + (size_t)b0 * sND,
            NN, DD, sNNe, sND, sND);
    }
    norm_add<<<dim3(BB * NN), 256, 0, stream>>>(out, img1);
}

// Round 3
// 301.634 us; speedup vs baseline: 1.1360x; 1.0945x over previous
//
#include <hip/hip_runtime.h>
#include <stdint.h>

// B=16, N=1024, D=768 fixed for this problem.
#define BB 16
#define NN 1024
#define DD 768

typedef unsigned short u16;
using bf16x8 = __attribute__((ext_vector_type(8))) __bf16;
using f32x4  = __attribute__((ext_vector_type(4))) float;

__device__ inline u16 f2bf(float x) {
    uint32_t u = __float_as_uint(x);
    u += 0x7fffu + ((u >> 16) & 1u);   // round-to-nearest-even
    return (u16)(u >> 16);
}

__device__ inline void gl_lds16(const void* g, void* l) {
    __builtin_amdgcn_global_load_lds(
        (__attribute__((address_space(1))) void*)g,
        (__attribute__((address_space(3))) void*)l,
        16, 0, 0);
}

__device__ inline void barrier_raw() {
    asm volatile("s_barrier" ::: "memory");
}

// ---------------------------------------------------------------------------
// K1: fp32 [B][N][D] -> bf16 [B][N][D] and bf16 transposed [B][D][N]
// grid (D/32, N/32, B), block 256
// ---------------------------------------------------------------------------
__global__ __launch_bounds__(256) void cast_transpose(
    const float* __restrict__ in, u16* __restrict__ outb, u16* __restrict__ outT)
{
    __shared__ u16 tile[32][33];
    const int b  = blockIdx.z;
    const int n0 = blockIdx.y * 32;
    const int d0 = blockIdx.x * 32;
    const int t  = threadIdx.x;
    const int c  = t & 31;
    const int r0 = t >> 5;   // 0..7

    const float* src = in + ((size_t)b * NN + n0) * DD + d0;
#pragma unroll
    for (int i = 0; i < 4; ++i) {
        int r = r0 + 8 * i;
        float x = src[(size_t)r * DD + c];
        u16 h = f2bf(x);
        outb[((size_t)b * NN + n0 + r) * DD + d0 + c] = h;
        tile[r][c] = h;
    }
    __syncthreads();
#pragma unroll
    for (int i = 0; i < 4; ++i) {
        int r = r0 + 8 * i;   // d offset within tile
        outT[((size_t)b * DD + d0 + r) * NN + n0 + c] = tile[c][r];
    }
}

// ---------------------------------------------------------------------------
// K2: C[b][i][j] = sum_k A[b][i][k] * B[b][j][k]   (both row-major, K contig)
// tile 128x128, BK=64, 4 waves, 16x16x32 MFMA, XOR-swizzled LDS.
// 2-phase double-buffered prefetch: STAGE(next) issued before compute(cur),
// counted s_waitcnt vmcnt(8) (never 0 in main loop), raw s_barrier
// (NOT __syncthreads, which drains vmcnt(0) and defeats the pipeline).
// XCD-aware bijective block swizzle (T1), batch decoded slowest.
// grid (Ncols/128, M/128, batch), block 256
// ---------------------------------------------------------------------------
__global__ __launch_bounds__(256) void gemm_bt(
    const u16* __restrict__ A, const u16* __restrict__ B, float* __restrict__ C,
    const int K, const int ldc, const size_t sA, const size_t sB, const size_t sC)
{
    __shared__ u16 lsA0[128 * 64];
    __shared__ u16 lsB0[128 * 64];
    __shared__ u16 lsA1[128 * 64];
    __shared__ u16 lsB1[128 * 64];

    // --- XCD swizzle: dispatch-order id -> owned tile id ---
    const int gx = gridDim.x, gy = gridDim.y;
    const int nwg = gx * gy * gridDim.z;
    int bid = blockIdx.x + gx * (blockIdx.y + gy * blockIdx.z);
    bid = (bid & 7) * (nwg >> 3) + (bid >> 3);
    const int gxy = gx * gy;
    const int bz = bid / gxy;
    const int rem = bid - bz * gxy;
    const int by = rem / gx;
    const int bx = rem - by * gx;

    const int tid = threadIdx.x;
    const int w  = tid >> 6;
    const int l  = tid & 63;
    const int wm = w >> 1, wn = w & 1;

    const u16* Ab = A + (size_t)bz * sA + (size_t)by * 128 * K;
    const u16* Bb = B + (size_t)bz * sB + (size_t)bx * 128 * K;

    // staging: each wave issues 4 A-loads + 4 B-loads of 16B x 64 lanes (1KB)
    const int lrow  = l >> 3;         // 0..7 (row within 8-row chunk)
    const int lslot = l & 7;          // 16B slot within 128B row
    const int gslot = lslot ^ lrow;   // pre-swizzled global source slot

    const u16* pA[4]; const u16* pB[4];
#pragma unroll
    for (int i = 0; i < 4; ++i) {
        int row = w * 32 + i * 8 + lrow;          // 0..127
        pA[i] = Ab + (size_t)row * K + gslot * 8;
        pB[i] = Bb + (size_t)row * K + gslot * 8;
    }

    auto stage = [&](u16* la, u16* lb) {
#pragma unroll
        for (int i = 0; i < 4; ++i) {
            gl_lds16(pA[i], (char*)la + (w * 4 + i) * 1024);
            gl_lds16(pB[i], (char*)lb + (w * 4 + i) * 1024);
            pA[i] += 64;
            pB[i] += 64;
        }
    };

    // read-side fragment addressing
    const int lg = l >> 4;   // 0..3
    const int lr = l & 15;
    int rbA[4], rxA[4], rbB[4], rxB[4];
#pragma unroll
    for (int m = 0; m < 4; ++m) {
        int rA = wm * 64 + m * 16 + lr;
        rbA[m] = rA * 128; rxA[m] = rA & 7;
        int rB = wn * 64 + m * 16 + lr;
        rbB[m] = rB * 128; rxB[m] = rB & 7;
    }

    f32x4 acc[4][4];
#pragma unroll
    for (int i = 0; i < 4; ++i)
#pragma unroll
        for (int j = 0; j < 4; ++j) acc[i][j] = (f32x4){0.f, 0.f, 0.f, 0.f};

    auto compute = [&](const u16* lAp, const u16* lBp) {
        const char* lA = (const char*)lAp;
        const char* lB = (const char*)lBp;
#pragma unroll
        for (int kk = 0; kk < 2; ++kk) {
            bf16x8 a[4], b[4];
#pragma unroll
            for (int m = 0; m < 4; ++m) {
                int slot = kk * 4 + lg;
                a[m] = *(const bf16x8*)(lA + rbA[m] + ((slot ^ rxA[m]) << 4));
                b[m] = *(const bf16x8*)(lB + rbB[m] + ((slot ^ rxB[m]) << 4));
            }
#pragma unroll
            for (int m = 0; m < 4; ++m)
#pragma unroll
                for (int n = 0; n < 4; ++n)
                    acc[m][n] = __builtin_amdgcn_mfma_f32_16x16x32_bf16(
                        a[m], b[n], acc[m][n], 0, 0, 0);
        }
    };

    const int ksteps = K >> 6;    // 12 or 16, always even
    stage(lsA0, lsB0);            // prologue: K-step 0 into buf0

    for (int kt = 0; kt < ksteps; kt += 2) {
        // even step: stage kt+1 into buf1, compute buf0
        stage(lsA1, lsB1);
        asm volatile("s_waitcnt vmcnt(8)" ::: "memory");  // buf0 loads landed
        barrier_raw();
        compute(lsA0, lsB0);
        barrier_raw();            // all reads of buf0 done -> safe to overwrite

        // odd step: stage kt+2 into buf0 (if any), compute buf1
        if (kt + 2 < ksteps) {
            stage(lsA0, lsB0);
            asm volatile("s_waitcnt vmcnt(8)" ::: "memory");
        } else {
            asm volatile("s_waitcnt vmcnt(0)" ::: "memory");
        }
        barrier_raw();
        compute(lsA1, lsB1);
        barrier_raw();
    }

    float* Cb = C + (size_t)bz * sC;
    const int crow = by * 128 + wm * 64 + lg * 4;
    const int ccol = bx * 128 + wn * 64 + lr;
#pragma unroll
    for (int m = 0; m < 4; ++m)
#pragma unroll
        for (int n = 0; n < 4; ++n)
#pragma unroll
            for (int r = 0; r < 4; ++r)
                Cb[(size_t)(crow + m * 16 + r) * ldc + ccol + n * 16] = acc[m][n][r];
}

// ---------------------------------------------------------------------------
// K3: row softmax over 1024 fp32 -> bf16. grid = rows, block 256
// ---------------------------------------------------------------------------
__global__ __launch_bounds__(256) void softmax_rows(
    const float* __restrict__ sim, u16* __restrict__ attn)
{
    __shared__ float red[4];
    const size_t row = blockIdx.x;
    const float* p = sim + row * NN;
    const int t = threadIdx.x;

    float v0 = p[t], v1 = p[t + 256], v2 = p[t + 512], v3 = p[t + 768];
    float m = fmaxf(fmaxf(v0, v1), fmaxf(v2, v3));
#pragma unroll
    for (int o = 32; o > 0; o >>= 1) m = fmaxf(m, __shfl_xor(m, o, 64));
    if ((t & 63) == 0) red[t >> 6] = m;
    __syncthreads();
    m = fmaxf(fmaxf(red[0], red[1]), fmaxf(red[2], red[3]));
    __syncthreads();

    float e0 = __expf(v0 - m), e1 = __expf(v1 - m);
    float e2 = __expf(v2 - m), e3 = __expf(v3 - m);
    float s = e0 + e1 + e2 + e3;
#pragma unroll
    for (int o = 32; o > 0; o >>= 1) s += __shfl_xor(s, o, 64);
    if ((t & 63) == 0) red[t >> 6] = s;
    __syncthreads();
    s = red[0] + red[1] + red[2] + red[3];
    const float inv = 1.0f / s;

    u16* q = attn + row * NN;
    q[t]       = f2bf(e0 * inv);
    q[t + 256] = f2bf(e1 * inv);
    q[t + 512] = f2bf(e2 * inv);
    q[t + 768] = f2bf(e3 * inv);
}

// ---------------------------------------------------------------------------
// K4: in-place io = io/max(||io||,eps) + 2*img, per row of 768. grid = B*N
// ---------------------------------------------------------------------------
__global__ __launch_bounds__(256) void norm_add(
    float* __restrict__ io, const float* __restrict__ img)
{
    __shared__ float red[4];
    const size_t row = blockIdx.x;
    float* p = io + row * DD;
    const float* q = img + row * DD;
    const int t = threadIdx.x;

    float x0 = p[t], x1 = p[t + 256], x2 = p[t + 512];
    float s = x0 * x0 + x1 * x1 + x2 * x2;
#pragma unroll
    for (int o = 32; o > 0; o >>= 1) s += __shfl_xor(s, o, 64);
    if ((t & 63) == 0) red[t >> 6] = s;
    __syncthreads();
    s = red[0] + red[1] + red[2] + red[3];
    const float sc = 1.0f / fmaxf(sqrtf(s), 1e-12f);

    p[t]       = x0 * sc + 2.0f * q[t];
    p[t + 256] = x1 * sc + 2.0f * q[t + 256];
    p[t + 512] = x2 * sc + 2.0f * q[t + 512];
}

// ---------------------------------------------------------------------------
extern "C" void kernel_launch(void* const* d_in, const int* in_sizes, int n_in,
                              void* d_out, int out_size, void* d_ws, size_t ws_size,
                              hipStream_t stream)
{
    const float* img1 = (const float*)d_in[0];
    const float* img2 = (const float*)d_in[1];
    float* out = (float*)d_out;

    const size_t NBD = (size_t)BB * NN * DD;       // 12582912 elems
    u16* i1b = (u16*)d_ws;
    u16* i2b = i1b + NBD;
    u16* i1t = i2b + NBD;
    u16* i2t = i1t + NBD;
    char* rest = (char*)(i2t + NBD);
    const size_t baseBytes = 4 * NBD * sizeof(u16);

    int CB = 16;
    while (CB > 1 && baseBytes + (size_t)CB * NN * NN * 6 > ws_size) CB >>= 1;

    float* sim = (float*)rest;
    u16* attn = (u16*)(rest + (size_t)CB * NN * NN * 4);

    const size_t sND = (size_t)NN * DD;   // 786432
    const size_t sNNe = (size_t)NN * NN;  // 1048576

    cast_transpose<<<dim3(DD / 32, NN / 32, BB), 256, 0, stream>>>(img1, i1b, i1t);
    cast_transpose<<<dim3(DD / 32, NN / 32, BB), 256, 0, stream>>>(img2, i2b, i2t);

    // Direction A: Q=img1, K/V=img2 -> output slot 1 (out2)
    for (int b0 = 0; b0 < BB; b0 += CB) {
        gemm_bt<<<dim3(NN / 128, NN / 128, CB), 256, 0, stream>>>(
            i1b + (size_t)b0 * sND, i2b + (size_t)b0 * sND, sim,
            DD, NN, sND, sND, sNNe);
        softmax_rows<<<dim3(CB * NN), 256, 0, stream>>>(sim, attn);
        gemm_bt<<<dim3(DD / 128, NN / 128, CB), 256, 0, stream>>>(
            attn, i2t + (size_t)b0 * sND, out + NBD + (size_t)b0 * sND,
            NN, DD, sNNe, sND, sND);
    }
    norm_add<<<dim3(BB * NN), 256, 0, stream>>>(out + NBD, img2);

    // Direction B: Q=img2, K/V=img1 -> output slot 0 (out1)
    for (int b0 = 0; b0 < BB; b0 += CB) {
        gemm_bt<<<dim3(NN / 128, NN / 128, CB), 256, 0, stream>>>(
            i2b + (size_t)b0 * sND, i1b + (size_t)b0 * sND, sim,
            DD, NN, sND, sND, sNNe);
        softmax_rows<<<dim3(CB * NN), 256, 0, stream>>>(sim, attn);
        gemm_bt<<<dim3(DD / 128, NN / 128, CB), 256, 0, stream>>>(
            attn, i1t + (size_t)b0 * sND, out + (size_t)b0 * sND,
            NN, DD, sNNe, sND, sND);
    }
    norm_add<<<dim3(BB * NN), 256, 0, stream>>>(out, img1);
}

// Round 4
// 270.145 us; speedup vs baseline: 1.2684x; 1.1166x over previous
//
#include <hip/hip_runtime.h>
#include <stdint.h>

// B=16, N=1024, D=768 fixed for this problem.
#define BB 16
#define NN 1024
#define DD 768

typedef unsigned short u16;
using bf16x8 = __attribute__((ext_vector_type(8))) __bf16;
using f32x4  = __attribute__((ext_vector_type(4))) float;
using u16x8  = __attribute__((ext_vector_type(8))) unsigned short;

__device__ inline u16 f2bf(float x) {
    uint32_t u = __float_as_uint(x);
    u += 0x7fffu + ((u >> 16) & 1u);   // round-to-nearest-even
    return (u16)(u >> 16);
}

__device__ inline void gl_lds16(const void* g, void* l) {
    __builtin_amdgcn_global_load_lds(
        (__attribute__((address_space(1))) void*)g,
        (__attribute__((address_space(3))) void*)l,
        16, 0, 0);
}

__device__ inline void barrier_raw() {
    asm volatile("s_barrier" ::: "memory");
}

// ---------------------------------------------------------------------------
// K1: fp32 [B][N][D] -> bf16 [B][N][D] and bf16 transposed [B][D][N]
// 64x64 tile, vectorized: float4 loads, 16B stores on both outputs.
// grid (D/64, N/64, B), block 256
// ---------------------------------------------------------------------------
__global__ __launch_bounds__(256) void cast_transpose(
    const float* __restrict__ in, u16* __restrict__ outb, u16* __restrict__ outT)
{
    __shared__ u16 tl[64][72];   // [d][n], row = 144 B (16-aligned)
    const int b  = blockIdx.z;
    const int n0 = blockIdx.y * 64;
    const int d0 = blockIdx.x * 64;
    const int t  = threadIdx.x;

    {
        const int r  = t >> 2;        // n-row 0..63
        const int cg = t & 3;         // 16-wide d group
        const float* src = in + ((size_t)b * NN + n0 + r) * DD + d0 + cg * 16;
        u16 h[16];
#pragma unroll
        for (int j = 0; j < 4; ++j) {
            float4 v = *(const float4*)(src + j * 4);
            h[j * 4 + 0] = f2bf(v.x);
            h[j * 4 + 1] = f2bf(v.y);
            h[j * 4 + 2] = f2bf(v.z);
            h[j * 4 + 3] = f2bf(v.w);
        }
        u16* dst = outb + ((size_t)b * NN + n0 + r) * DD + d0 + cg * 16;
        u16x8 p0, p1;
#pragma unroll
        for (int j = 0; j < 8; ++j) { p0[j] = h[j]; p1[j] = h[j + 8]; }
        *(u16x8*)(dst)     = p0;
        *(u16x8*)(dst + 8) = p1;
#pragma unroll
        for (int j = 0; j < 16; ++j) tl[cg * 16 + j][r] = h[j];
    }
    __syncthreads();
    {
        const int d  = t >> 2;        // 0..63
        const int ng = t & 3;         // 16-wide n group
        u16x8 a0 = *(const u16x8*)&tl[d][ng * 16];
        u16x8 a1 = *(const u16x8*)&tl[d][ng * 16 + 8];
        u16* dst = outT + ((size_t)b * DD + d0 + d) * NN + n0 + ng * 16;
        *(u16x8*)(dst)     = a0;
        *(u16x8*)(dst + 8) = a1;
    }
}

// ---------------------------------------------------------------------------
// K2: C[b][i][j] = sum_k A[b][i][k] * B[b][j][k]   (both row-major, K contig)
// Tile 256 x (NFRAG*64), BK=64, 8 waves (512 thr, 2Mx4N), 16x16x32 MFMA.
// 2-phase double-buffered: STAGE(next) before compute(cur), counted
// s_waitcnt vmcnt(4+NFRAG) (never 0 in main loop), raw s_barrier.
// XOR-swizzled LDS (linear dest + pre-swizzled global src + swizzled read).
// XCD-aware bijective block swizzle, batch decoded slowest.
// grid (Ncols/(NFRAG*64), M/256, batch), block 512
// ---------------------------------------------------------------------------
template<int NFRAG>
__global__ __launch_bounds__(512) void gemm_bt(
    const u16* __restrict__ A, const u16* __restrict__ B, float* __restrict__ C,
    const int K, const int ldc, const size_t sA, const size_t sB, const size_t sC)
{
    __shared__ u16 lsA[2][256 * 64];
    __shared__ u16 lsB[2][NFRAG * 64 * 64];

    // --- XCD swizzle: dispatch-order id -> owned tile id ---
    const int gx = gridDim.x, gy = gridDim.y;
    const int nwg = gx * gy * gridDim.z;
    int bid = blockIdx.x + gx * (blockIdx.y + gy * blockIdx.z);
    bid = (bid & 7) * (nwg >> 3) + (bid >> 3);
    const int gxy = gx * gy;
    const int bz = bid / gxy;
    const int rem = bid - bz * gxy;
    const int by = rem / gx;
    const int bx = rem - by * gx;

    const int tid = threadIdx.x;
    const int w  = tid >> 6;          // 0..7
    const int l  = tid & 63;
    const int wm = w >> 2;            // 0..1 (row half)
    const int wn = w & 3;             // 0..3 (col quarter)

    const u16* Ab = A + (size_t)bz * sA + (size_t)by * 256 * K;
    const u16* Bb = B + (size_t)bz * sB + (size_t)bx * (NFRAG * 64) * K;

    // staging: thread tid covers row (i*64 + tid>>3), 16B slot (tid&7).
    // LDS dest is linear; swizzle realized by pre-swizzling the GLOBAL slot.
    const int trow  = tid >> 3;        // 0..63
    const int tslot = tid & 7;
    const int gslot = tslot ^ (trow & 7);

    const u16* pA[4]; const u16* pB[NFRAG];
#pragma unroll
    for (int i = 0; i < 4; ++i)
        pA[i] = Ab + (size_t)(i * 64 + trow) * K + gslot * 8;
#pragma unroll
    for (int i = 0; i < NFRAG; ++i)
        pB[i] = Bb + (size_t)(i * 64 + trow) * K + gslot * 8;

    auto stage = [&](int buf) {
#pragma unroll
        for (int i = 0; i < 4; ++i) {
            gl_lds16(pA[i], (char*)lsA[buf] + i * 8192 + w * 1024);
            pA[i] += 64;
        }
#pragma unroll
        for (int i = 0; i < NFRAG; ++i) {
            gl_lds16(pB[i], (char*)lsB[buf] + i * 8192 + w * 1024);
            pB[i] += 64;
        }
    };

    // read-side fragment addressing
    const int lg = l >> 4;   // 0..3
    const int lr = l & 15;
    int rbA[8], rxA[8], rbB[NFRAG], rxB[NFRAG];
#pragma unroll
    for (int m = 0; m < 8; ++m) {
        int rA = wm * 128 + m * 16 + lr;
        rbA[m] = rA * 128; rxA[m] = rA & 7;
    }
#pragma unroll
    for (int n = 0; n < NFRAG; ++n) {
        int rB = wn * (NFRAG * 16) + n * 16 + lr;
        rbB[n] = rB * 128; rxB[n] = rB & 7;
    }

    f32x4 acc[8][NFRAG];
#pragma unroll
    for (int i = 0; i < 8; ++i)
#pragma unroll
        for (int j = 0; j < NFRAG; ++j) acc[i][j] = (f32x4){0.f, 0.f, 0.f, 0.f};

    auto compute = [&](int buf) {
        const char* lA = (const char*)lsA[buf];
        const char* lB = (const char*)lsB[buf];
#pragma unroll
        for (int kk = 0; kk < 2; ++kk) {
            const int slot = kk * 4 + lg;
            bf16x8 a[8], b[NFRAG];
#pragma unroll
            for (int m = 0; m < 8; ++m)
                a[m] = *(const bf16x8*)(lA + rbA[m] + ((slot ^ rxA[m]) << 4));
#pragma unroll
            for (int n = 0; n < NFRAG; ++n)
                b[n] = *(const bf16x8*)(lB + rbB[n] + ((slot ^ rxB[n]) << 4));
#pragma unroll
            for (int m = 0; m < 8; ++m)
#pragma unroll
                for (int n = 0; n < NFRAG; ++n)
                    acc[m][n] = __builtin_amdgcn_mfma_f32_16x16x32_bf16(
                        a[m], b[n], acc[m][n], 0, 0, 0);
        }
    };

    auto wait_counted = []() {
        if constexpr (NFRAG == 4)
            asm volatile("s_waitcnt vmcnt(8)" ::: "memory");
        else
            asm volatile("s_waitcnt vmcnt(7)" ::: "memory");
    };

    const int ksteps = K >> 6;    // 12 or 16, always even
    stage(0);                     // prologue: K-step 0 into buf0

    for (int kt = 0; kt < ksteps; kt += 2) {
        // even step: stage kt+1 into buf1, compute buf0
        stage(1);
        wait_counted();           // buf0 loads landed
        barrier_raw();
        compute(0);
        barrier_raw();            // reads of buf0 done -> safe to overwrite

        // odd step: stage kt+2 into buf0 (if any), compute buf1
        if (kt + 2 < ksteps) {
            stage(0);
            wait_counted();
        } else {
            asm volatile("s_waitcnt vmcnt(0)" ::: "memory");
        }
        barrier_raw();
        compute(1);
        barrier_raw();
    }

    float* Cb = C + (size_t)bz * sC;
    const int crow = by * 256 + wm * 128 + lg * 4;
    const int ccol = bx * (NFRAG * 64) + wn * (NFRAG * 16) + lr;
#pragma unroll
    for (int m = 0; m < 8; ++m)
#pragma unroll
        for (int n = 0; n < NFRAG; ++n)
#pragma unroll
            for (int r = 0; r < 4; ++r)
                Cb[(size_t)(crow + m * 16 + r) * ldc + ccol + n * 16] = acc[m][n][r];
}

// ---------------------------------------------------------------------------
// K3: row softmax over 1024 fp32 -> bf16, vectorized. grid = rows, block 256
// ---------------------------------------------------------------------------
__global__ __launch_bounds__(256) void softmax_rows(
    const float* __restrict__ sim, u16* __restrict__ attn)
{
    __shared__ float red[4];
    const size_t row = blockIdx.x;
    const int t = threadIdx.x;

    float4 v = *(const float4*)(sim + row * NN + t * 4);
    float m = fmaxf(fmaxf(v.x, v.y), fmaxf(v.z, v.w));
#pragma unroll
    for (int o = 32; o > 0; o >>= 1) m = fmaxf(m, __shfl_xor(m, o, 64));
    if ((t & 63) == 0) red[t >> 6] = m;
    __syncthreads();
    m = fmaxf(fmaxf(red[0], red[1]), fmaxf(red[2], red[3]));
    __syncthreads();

    float e0 = __expf(v.x - m), e1 = __expf(v.y - m);
    float e2 = __expf(v.z - m), e3 = __expf(v.w - m);
    float s = e0 + e1 + e2 + e3;
#pragma unroll
    for (int o = 32; o > 0; o >>= 1) s += __shfl_xor(s, o, 64);
    if ((t & 63) == 0) red[t >> 6] = s;
    __syncthreads();
    s = red[0] + red[1] + red[2] + red[3];
    const float inv = 1.0f / s;

    ushort4 o4;
    o4.x = f2bf(e0 * inv); o4.y = f2bf(e1 * inv);
    o4.z = f2bf(e2 * inv); o4.w = f2bf(e3 * inv);
    *(ushort4*)(attn + row * NN + t * 4) = o4;
}

// ---------------------------------------------------------------------------
// K4: in-place io = io/max(||io||,eps) + 2*img, per row of 768, vectorized.
// grid = B*N, block 192 (192*4 = 768)
// ---------------------------------------------------------------------------
__global__ __launch_bounds__(192) void norm_add(
    float* __restrict__ io, const float* __restrict__ img)
{
    __shared__ float red[3];
    const size_t row = blockIdx.x;
    float* p = io + row * DD;
    const float* q = img + row * DD;
    const int t = threadIdx.x;

    float4 x = *(const float4*)(p + t * 4);
    float s = x.x * x.x + x.y * x.y + x.z * x.z + x.w * x.w;
#pragma unroll
    for (int o = 32; o > 0; o >>= 1) s += __shfl_xor(s, o, 64);
    if ((t & 63) == 0) red[t >> 6] = s;
    __syncthreads();
    s = red[0] + red[1] + red[2];
    const float sc = 1.0f / fmaxf(sqrtf(s), 1e-12f);

    float4 g = *(const float4*)(q + t * 4);
    float4 o4;
    o4.x = x.x * sc + 2.0f * g.x;
    o4.y = x.y * sc + 2.0f * g.y;
    o4.z = x.z * sc + 2.0f * g.z;
    o4.w = x.w * sc + 2.0f * g.w;
    *(float4*)(p + t * 4) = o4;
}

// ---------------------------------------------------------------------------
extern "C" void kernel_launch(void* const* d_in, const int* in_sizes, int n_in,
                              void* d_out, int out_size, void* d_ws, size_t ws_size,
                              hipStream_t stream)
{
    const float* img1 = (const float*)d_in[0];
    const float* img2 = (const float*)d_in[1];
    float* out = (float*)d_out;

    const size_t NBD = (size_t)BB * NN * DD;       // 12582912 elems
    u16* i1b = (u16*)d_ws;
    u16* i2b = i1b + NBD;
    u16* i1t = i2b + NBD;
    u16* i2t = i1t + NBD;
    char* rest = (char*)(i2t + NBD);
    const size_t baseBytes = 4 * NBD * sizeof(u16);

    int CB = 16;
    while (CB > 1 && baseBytes + (size_t)CB * NN * NN * 6 > ws_size) CB >>= 1;

    float* sim = (float*)rest;
    u16* attn = (u16*)(rest + (size_t)CB * NN * NN * 4);

    const size_t sND = (size_t)NN * DD;   // 786432
    const size_t sNNe = (size_t)NN * NN;  // 1048576

    cast_transpose<<<dim3(DD / 64, NN / 64, BB), 256, 0, stream>>>(img1, i1b, i1t);
    cast_transpose<<<dim3(DD / 64, NN / 64, BB), 256, 0, stream>>>(img2, i2b, i2t);

    // Direction A: Q=img1, K/V=img2 -> output slot 1 (out2)
    for (int b0 = 0; b0 < BB; b0 += CB) {
        gemm_bt<4><<<dim3(NN / 256, NN / 256, CB), 512, 0, stream>>>(
            i1b + (size_t)b0 * sND, i2b + (size_t)b0 * sND, sim,
            DD, NN, sND, sND, sNNe);
        softmax_rows<<<dim3(CB * NN), 256, 0, stream>>>(sim, attn);
        gemm_bt<3><<<dim3(DD / 192, NN / 256, CB), 512, 0, stream>>>(
            attn, i2t + (size_t)b0 * sND, out + NBD + (size_t)b0 * sND,
            NN, DD, sNNe, sND, sND);
    }
    norm_add<<<dim3(BB * NN), 192, 0, stream>>>(out + NBD, img2);

    // Direction B: Q=img2, K/V=img1 -> output slot 0 (out1)
    for (int b0 = 0; b0 < BB; b0 += CB) {
        gemm_bt<4><<<dim3(NN / 256, NN / 256, CB), 512, 0, stream>>>(
            i2b + (size_t)b0 * sND, i1b + (size_t)b0 * sND, sim,
            DD, NN, sND, sND, sNNe);
        softmax_rows<<<dim3(CB * NN), 256, 0, stream>>>(sim, attn);
        gemm_bt<3><<<dim3(DD / 192, NN / 256, CB), 512, 0, stream>>>(
            attn, i1t + (size_t)b0 * sND, out + (size_t)b0 * sND,
            NN, DD, sNNe, sND, sND);
    }
    norm_add<<<dim3(BB * NN), 192, 0, stream>>>(out, img1);
}